// Round 8
// baseline (225.754 us; speedup 1.0000x reference)
//
#include <hip/hip_runtime.h>
#include <climits>

#define VOXD 25
#define SLOT3 (VOXD*VOXD*VOXD)      // 15625
#define SLOTS (2*SLOT3)             // 31250
#define NCLS 8
#define NCODE 16
#define NBLK ((SLOTS + 255) / 256)  // 123
#define HB 2048                     // radix bins (11 bits)
#define FBK 64                      // fallback blocks per code

struct Scalars {
  double hub;
  double cosSum;
  int n1;
  int nmd;
  int missCount;
  int nPure;
  int binA, rA, binB, rB;
  float thresh;
  int pad;
};

__device__ __forceinline__ int voxslot(int b, int vx, int vy, int vz) {
  return ((b * VOXD + vx) * VOXD + vy) * VOXD + vz;
}

// ---- block-wide inclusive scan (int), 1024 threads = 16 waves ----
__device__ __forceinline__ int block_scan_i(int v, int* ws, int* total) {
  int lane = threadIdx.x & 63, w = threadIdx.x >> 6;
  int s = v;
  #pragma unroll
  for (int off = 1; off < 64; off <<= 1) {
    int t = __shfl_up(s, off, 64);
    if (lane >= off) s += t;
  }
  if (lane == 63) ws[w] = s;
  __syncthreads();
  if (threadIdx.x < 16) {
    int x = ws[threadIdx.x];
    #pragma unroll
    for (int off = 1; off < 16; off <<= 1) {
      int t = __shfl_up(x, off, 64);
      if (lane >= off) x += t;
    }
    ws[threadIdx.x] = x;
  }
  __syncthreads();
  if (w > 0) s += ws[w - 1];
  *total = ws[15];
  __syncthreads();
  return s;
}

// ---- 256-thread packed u64 scan (16 codes x 16-bit fields), 4 waves ----
__device__ __forceinline__ void scan4_256(unsigned long long v[4],
                                          unsigned long long* ws /*16*/) {
  int lane = threadIdx.x & 63, w = threadIdx.x >> 6;
  #pragma unroll
  for (int q = 0; q < 4; ++q) {
    unsigned long long s = v[q];
    #pragma unroll
    for (int off = 1; off < 64; off <<= 1) {
      unsigned long long t = __shfl_up(s, off, 64);
      if (lane >= off) s += t;
    }
    v[q] = s;
    if (lane == 63) ws[q * 4 + w] = s;
  }
  __syncthreads();
  if (threadIdx.x < 16) {
    int q = threadIdx.x >> 2, idx = threadIdx.x & 3;
    unsigned long long x = ws[q * 4 + idx];
    #pragma unroll
    for (int off = 1; off < 4; off <<= 1) {
      unsigned long long t = __shfl_up(x, off, 64);
      if (idx >= off) x += t;
    }
    ws[q * 4 + idx] = x;
  }
  __syncthreads();
  #pragma unroll
  for (int q = 0; q < 4; ++q) if (w > 0) v[q] += ws[q * 4 + w - 1];
}

// ---------------- K1: zero-init ----------------
__global__ void k_init(int* cnt, float* sx, float* sy, float* sz, int* lmask,
                       int* blCnt, float* blSum, int* cntAB, int* missCnt, Scalars* sc) {
  int i = blockIdx.x * blockDim.x + threadIdx.x;
  if (i < SLOTS) {
    cnt[i] = 0; sx[i] = 0.f; sy[i] = 0.f; sz[i] = 0.f; lmask[i] = 0;
  }
  if (i < 16) { blCnt[i] = 0; blSum[3*i] = 0.f; blSum[3*i+1] = 0.f; blSum[3*i+2] = 0.f; }
  if (i < NCODE) missCnt[i] = 0;
  if (i < 2) cntAB[i] = 0;
  if (i == 0) {
    sc->hub = 0.0; sc->cosSum = 0.0; sc->n1 = 0; sc->nmd = 0;
    sc->missCount = 0; sc->nPure = 0;
  }
}

// ---------------- K2: per-point scatter; label bitmask; LDS-agg (b,l) stats ------
__global__ void k_scatter(const float* __restrict__ grid, const int* __restrict__ label,
                          const int* __restrict__ batch,
                          int* cnt, float* sx, float* sy, float* sz, int* lmask,
                          int* blCnt, float* blSum, int n) {
  __shared__ int sCnt[NCODE];
  __shared__ float sSum[3 * NCODE];
  int tid = threadIdx.x;
  if (tid < NCODE) sCnt[tid] = 0;
  if (tid < 3 * NCODE) sSum[tid] = 0.f;
  __syncthreads();
  int i = blockIdx.x * blockDim.x + tid;
  if (i < n) {
    float gx = grid[3*i], gy = grid[3*i+1], gz = grid[3*i+2];
    int vx = (int)floorf(gx * (1.0f/16.0f));
    int vy = (int)floorf(gy * (1.0f/16.0f));
    int vz = (int)floorf(gz * (1.0f/16.0f));
    int b = batch[i], l = label[i];
    int s = voxslot(b, vx, vy, vz);
    atomicAdd(&cnt[s], 1);
    atomicAdd(&sx[s], gx); atomicAdd(&sy[s], gy); atomicAdd(&sz[s], gz);
    atomicOr(&lmask[s], 1 << l);
    int bl = b * NCLS + l;
    atomicAdd(&sCnt[bl], 1);
    atomicAdd(&sSum[3*bl], gx); atomicAdd(&sSum[3*bl+1], gy); atomicAdd(&sSum[3*bl+2], gz);
  }
  __syncthreads();
  if (tid < NCODE && sCnt[tid] != 0) atomicAdd(&blCnt[tid], sCnt[tid]);
  if (tid < 3 * NCODE && sSum[tid] != 0.f) atomicAdd(&blSum[tid], sSum[tid]);
}

// ---------------- K3a: consolidate slot table to float4 + per-block code counts --
__global__ void k_prep(const int* cnt, const float* sx, const float* sy, const float* sz,
                       const int* lmask, float4* ctr, int* blockCnt) {
  __shared__ int sc16[NCODE];
  if (threadIdx.x < NCODE) sc16[threadIdx.x] = 0;
  __syncthreads();
  int s = blockIdx.x * 256 + threadIdx.x;
  if (s < SLOTS) {
    int c = cnt[s];
    float4 v = make_float4(0.f, 0.f, 0.f, __int_as_float(-2));
    if (c > 0) {
      float fc = (float)c;
      float cx = __fdiv_rn(sx[s], fc);
      float cy = __fdiv_rn(sy[s], fc);
      float cz = __fdiv_rn(sz[s], fc);
      int m = lmask[s];
      bool pure = (m & (m - 1)) == 0;
      int lbl = __ffs(m) - 1;
      int meta = pure ? lbl : -1;
      v = make_float4(cx, cy, cz, __int_as_float(meta));
      if (pure) atomicAdd(&sc16[(s / SLOT3) * NCLS + lbl], 1);
    }
    ctr[s] = v;
  }
  __syncthreads();
  if (threadIdx.x < NCODE) blockCnt[blockIdx.x * NCODE + threadIdx.x] = sc16[threadIdx.x];
}

// ---------------- K3b: bases per (block,code) and per code -----------------------
__global__ void k_bases(const int* blockCnt, int* blockBase, int* codeBase,
                        int* codeCnt, Scalars* sc) {
  __shared__ int tot[NCODE];
  int c = threadIdx.x;
  if (c < NCODE) {
    int run = 0;
    for (int b = 0; b < NBLK; ++b) {
      blockBase[b * NCODE + c] = run;
      run += blockCnt[b * NCODE + c];
    }
    tot[c] = run;
  }
  __syncthreads();
  if (c == 0) {
    int cum = 0;
    for (int k = 0; k < NCODE; ++k) { codeBase[k] = cum; codeCnt[k] = tot[k]; cum += tot[k]; }
    sc->nPure = cum;
  }
}

// ---------------- K4: compact pure clusters into per-code buckets (float4) -------
__global__ void k_compact(const float4* __restrict__ ctr,
                          const int* blockBase, const int* codeBase, float4* pC) {
  __shared__ unsigned long long ws[16];
  int s = blockIdx.x * 256 + threadIdx.x;
  int f = 0, code = 0;
  float4 cv = make_float4(0.f, 0.f, 0.f, 0.f);
  if (s < SLOTS) {
    cv = ctr[s];
    int meta = __float_as_int(cv.w);
    if (meta >= 0) { f = 1; code = (s / SLOT3) * NCLS + meta; }
  }
  unsigned long long v[4] = {0ULL, 0ULL, 0ULL, 0ULL};
  if (f) v[code >> 2] = 1ULL << (16 * (code & 3));
  scan4_256(v, ws);
  if (f) {
    int rank = (int)((v[code >> 2] >> (16 * (code & 3))) & 0xFFFFULL) - 1;
    int pos = codeBase[code] + blockBase[blockIdx.x * NCODE + code] + rank;
    float c2 = __fadd_rn(__fadd_rn(__fmul_rn(cv.x,cv.x), __fmul_rn(cv.y,cv.y)),
                         __fmul_rn(cv.z,cv.z));
    pC[pos] = make_float4(cv.x, cv.y, cv.z, c2);
  }
}

// ---------------- K5: probe targets + per-code block-aggregated miss lists -------
__global__ void k_targets(const float* __restrict__ grid, const int* __restrict__ label,
                          const int* __restrict__ batch,
                          const float4* __restrict__ ctr,
                          const int* __restrict__ blCnt, const float* __restrict__ blSum,
                          float* tgt, float* mag,
                          int* missPart, int* missCnt, int mstride, int n) {
  __shared__ int wCnt[4][NCODE];
  __shared__ int gBase[NCODE];
  int tid = threadIdx.x, lane = tid & 63, w = tid >> 6;
  int i = blockIdx.x * blockDim.x + tid;
  bool active = (i < n);
  bool miss = false;
  int mcode = -1;

  if (active) {
    float gx = grid[3*i], gy = grid[3*i+1], gz = grid[3*i+2];
    int vx = (int)floorf(gx * (1.0f/16.0f));
    int vy = (int)floorf(gy * (1.0f/16.0f));
    int vz = (int)floorf(gz * (1.0f/16.0f));
    int b = batch[i], l = label[i];
    int s = voxslot(b, vx, vy, vz);

    float4 own = ctr[s];
    bool purept = (__float_as_int(own.w) >= 0);

    int bl = b * NCLS + l;
    float fbc = (float)max(blCnt[bl], 1);
    float gcx = __fdiv_rn(blSum[3*bl],   fbc);
    float gcy = __fdiv_rn(blSum[3*bl+1], fbc);
    float gcz = __fdiv_rn(blSum[3*bl+2], fbc);

    float dx = __fsub_rn(gcx, own.x);
    float dy = __fsub_rn(gcy, own.y);
    float dz = __fsub_rn(gcz, own.z);
    int sgx = (dx > 0.f) ? 1 : ((dx < 0.f) ? -1 : 0);
    int sgy = (dy > 0.f) ? 1 : ((dy < 0.f) ? -1 : 0);
    int sgz = (dz > 0.f) ? 1 : ((dz < 0.f) ? -1 : 0);

    int ax1 = vx + sgx,     ay1 = vy + sgy,     az1 = vz + sgz;
    int ax2 = vx + 2 * sgx, ay2 = vy + 2 * sgy, az2 = vz + 2 * sgz;
    bool v1 = (unsigned)ax1 < (unsigned)VOXD && (unsigned)ay1 < (unsigned)VOXD &&
              (unsigned)az1 < (unsigned)VOXD;
    bool v2 = (unsigned)ax2 < (unsigned)VOXD && (unsigned)ay2 < (unsigned)VOXD &&
              (unsigned)az2 < (unsigned)VOXD;

    float4 q1 = make_float4(0.f, 0.f, 0.f, __int_as_float(-3));
    float4 q2 = q1;
    if (v1) q1 = ctr[voxslot(b, ax1, ay1, az1)];
    if (v2) q2 = ctr[voxslot(b, ax2, ay2, az2)];

    bool hit1 = v1 && (__float_as_int(q1.w) == l);
    bool hit2 = v2 && (__float_as_int(q2.w) == l);
    bool hit = hit1 || hit2;

    float tx = hit1 ? q1.x : (hit2 ? q2.x : gx);
    float ty = hit1 ? q1.y : (hit2 ? q2.y : gy);
    float tz = hit1 ? q1.z : (hit2 ? q2.z : gz);

    tgt[3*i] = tx; tgt[3*i+1] = ty; tgt[3*i+2] = tz;
    miss = (!purept && !hit);
    if (miss) {
      mcode = bl;
    } else {
      float tox = __fsub_rn(tx, gx), toy = __fsub_rn(ty, gy), toz = __fsub_rn(tz, gz);
      float ssq = __fadd_rn(__fadd_rn(__fmul_rn(tox,tox), __fmul_rn(toy,toy)),
                            __fmul_rn(toz,toz));
      float m = (ssq > 0.f) ? sqrtf(ssq) : 0.f;
      mag[i] = m;
    }
  }
  // per-wave per-code counts + in-wave rank
  int myrank = 0;
  #pragma unroll
  for (int c = 0; c < NCODE; ++c) {
    unsigned long long mb = __ballot(mcode == c);
    if (lane == 0) wCnt[w][c] = __popcll(mb);
    if (mcode == c) myrank = __popcll(mb & ((1ULL << lane) - 1ULL));
  }
  __syncthreads();
  if (tid < NCODE) {
    int tot = wCnt[0][tid] + wCnt[1][tid] + wCnt[2][tid] + wCnt[3][tid];
    gBase[tid] = (tot > 0) ? atomicAdd(&missCnt[tid], tot) : 0;
  }
  __syncthreads();
  if (miss) {
    int base = gBase[mcode];
    for (int q = 0; q < 4; ++q) if (q < w) base += wCnt[q][mcode];
    missPart[mcode * mstride + base + myrank] = i;
  }
}

// ---------------- K6: fallback — per-code blocks, thread-per-miss, LDS tiles -----
__global__ void __launch_bounds__(256) k_fallback(
    const float* __restrict__ grid,
    const float4* __restrict__ pC,
    const int* __restrict__ codeBase, const int* __restrict__ codeCnt,
    const int* __restrict__ missPart, const int* __restrict__ missCnt,
    float* tgt, float* mag, int mstride) {
  __shared__ float4 tile[1024];
  int c = blockIdx.x / FBK;
  int y = blockIdx.x % FBK;
  int mc = missCnt[c];
  if (y * 256 >= mc) return;           // uniform per block
  int cc = codeCnt[c];
  int j0 = codeBase[c];
  const int* mlist = missPart + c * mstride;

  for (int base = y * 256; base < mc; base += FBK * 256) {
    int t = base + threadIdx.x;
    bool valid = (t < mc);
    int idx = 0;
    float gx = 0.f, gy = 0.f, gz = 0.f, p2 = 0.f;
    if (valid) {
      idx = mlist[t];
      gx = grid[3*idx]; gy = grid[3*idx+1]; gz = grid[3*idx+2];
      p2 = __fadd_rn(__fadd_rn(__fmul_rn(gx,gx), __fmul_rn(gy,gy)), __fmul_rn(gz,gz));
    }
    float bestD = 1e38f;
    float bx = 0.f, by = 0.f, bz = 0.f;
    for (int tb = 0; tb < cc; tb += 1024) {
      int m = min(1024, cc - tb);
      for (int j = threadIdx.x; j < m; j += 256) tile[j] = pC[j0 + tb + j];
      __syncthreads();
      if (valid) {
        #pragma unroll 4
        for (int j = 0; j < m; ++j) {
          float4 cl = tile[j];
          float dot = __fadd_rn(__fadd_rn(__fmul_rn(gx,cl.x), __fmul_rn(gy,cl.y)),
                                __fmul_rn(gz,cl.z));
          float d2 = __fadd_rn(__fsub_rn(p2, __fmul_rn(2.0f, dot)), cl.w);
          if (d2 < bestD) { bestD = d2; bx = cl.x; by = cl.y; bz = cl.z; }
        }
      }
      __syncthreads();
    }
    if (valid) {
      if (bestD < 1e38f) {
        tgt[3*idx] = bx; tgt[3*idx+1] = by; tgt[3*idx+2] = bz;
        float tox = __fsub_rn(bx, gx), toy = __fsub_rn(by, gy), toz = __fsub_rn(bz, gz);
        float ssq = __fadd_rn(__fadd_rn(__fmul_rn(tox,tox), __fmul_rn(toy,toy)),
                              __fmul_rn(toz,toz));
        mag[idx] = (ssq > 0.f) ? sqrtf(ssq) : 0.f;
      } else {
        mag[idx] = 0.f;
      }
    }
  }
}

// ---------------- K7a: LDS-private coarse histogram (bits >> 21), no atomics -----
__global__ void __launch_bounds__(1024) k_hist(const float* __restrict__ mag,
                                               int* ghist, int n) {
  __shared__ int h[HB];
  for (int t = threadIdx.x; t < HB; t += 1024) h[t] = 0;
  __syncthreads();
  int i = blockIdx.x * 1024 + threadIdx.x;
  if (i < n) atomicAdd(&h[__float_as_uint(mag[i]) >> 21], 1);
  __syncthreads();
  for (int t = threadIdx.x; t < HB; t += 1024)
    ghist[blockIdx.x * HB + t] = h[t];
}

// ---------------- K7b: reduce block hists + find coarse bins of r0, r1 -----------
__global__ void __launch_bounds__(1024) k_redsel(const int* __restrict__ ghist, int nhb,
                                                 Scalars* sc, int r0, int r1) {
  __shared__ int ws[16];
  __shared__ int sBinA, sRA, sBinB, sRB;
  int t = threadIdx.x;
  int s0 = 0, s1 = 0;
  for (int b = 0; b < nhb; ++b) {
    int2 v = ((const int2*)(ghist + b * HB))[t];
    s0 += v.x; s1 += v.y;
  }
  int tot;
  int incl = block_scan_i(s0 + s1, ws, &tot);
  int b1 = incl - s1, b0 = b1 - s0;
  if (r0 >= b0 && r0 < b0 + s0) { sBinA = 2*t;   sRA = r0 - b0; }
  if (r0 >= b1 && r0 < b1 + s1) { sBinA = 2*t+1; sRA = r0 - b1; }
  if (r1 >= b0 && r1 < b0 + s0) { sBinB = 2*t;   sRB = r1 - b0; }
  if (r1 >= b1 && r1 < b1 + s1) { sBinB = 2*t+1; sRB = r1 - b1; }
  __syncthreads();
  if (t == 0) { sc->binA = sBinA; sc->rA = sRA; sc->binB = sBinB; sc->rB = sRB; }
}

// ---------------- K7c: gather candidate bit-patterns for the two coarse bins -----
__global__ void k_gather(const float* __restrict__ mag, const Scalars* sc,
                         unsigned* bufA, unsigned* bufB, int* cntAB, int n) {
  int i = blockIdx.x * blockDim.x + threadIdx.x;
  int lane = threadIdx.x & 63;
  unsigned bits = 0;
  bool inA = false, inB = false;
  if (i < n) {
    bits = __float_as_uint(mag[i]);
    unsigned c = bits >> 21;
    inA = (c == (unsigned)sc->binA);
    inB = (c == (unsigned)sc->binB);
  }
  {
    unsigned long long mb = __ballot(inA);
    int mc = __popcll(mb);
    int base = 0;
    if (lane == 0 && mc > 0) base = atomicAdd(&cntAB[0], mc);
    base = __shfl(base, 0, 64);
    if (inA) bufA[base + __popcll(mb & ((1ULL << lane) - 1ULL))] = bits;
  }
  {
    unsigned long long mb = __ballot(inB);
    int mc = __popcll(mb);
    int base = 0;
    if (lane == 0 && mc > 0) base = atomicAdd(&cntAB[1], mc);
    base = __shfl(base, 0, 64);
    if (inB) bufB[base + __popcll(mb & ((1ULL << lane) - 1ULL))] = bits;
  }
}

// ---------------- K7d helper: exact rank select within a coarse bin --------------
__device__ unsigned select_in_bin(const unsigned* __restrict__ buf, int cnt,
                                  int coarse, int rank, int* h, int* ws) {
  __shared__ int sSub, sSubR, sLow;
  for (int t = threadIdx.x; t < HB; t += 1024) h[t] = 0;
  __syncthreads();
  for (int t = threadIdx.x; t < cnt; t += 1024)
    atomicAdd(&h[(buf[t] >> 10) & 0x7FF], 1);
  __syncthreads();
  int t = threadIdx.x;
  int s0 = h[2*t], s1 = h[2*t+1];
  int tot;
  int incl = block_scan_i(s0 + s1, ws, &tot);
  int b1 = incl - s1, b0 = b1 - s0;
  if (rank >= b0 && rank < b0 + s0) { sSub = 2*t;   sSubR = rank - b0; }
  if (rank >= b1 && rank < b1 + s1) { sSub = 2*t+1; sSubR = rank - b1; }
  __syncthreads();
  int subv = sSub, subr = sSubR;
  h[t] = 0;
  __syncthreads();
  for (int q = threadIdx.x; q < cnt; q += 1024) {
    unsigned v = buf[q];
    if ((int)((v >> 10) & 0x7FF) == subv) atomicAdd(&h[v & 0x3FF], 1);
  }
  __syncthreads();
  int c = h[t];
  int tot2;
  int incl2 = block_scan_i(c, ws, &tot2);
  int lb = incl2 - c;
  if (subr >= lb && subr < lb + c) sLow = t;
  __syncthreads();
  return ((unsigned)coarse << 21) | ((unsigned)subv << 10) | (unsigned)sLow;
}

// ---------------- K7d: exact order statistics + lerp (numpy branch) --------------
__global__ void __launch_bounds__(1024) k_sel(const unsigned* __restrict__ bufA,
                                              const unsigned* __restrict__ bufB,
                                              const int* __restrict__ cntAB,
                                              Scalars* sc, double tfrac) {
  __shared__ int h[HB];
  __shared__ int ws[16];
  unsigned va = select_in_bin(bufA, cntAB[0], sc->binA, sc->rA, h, ws);
  __syncthreads();
  unsigned vb = select_in_bin(bufB, cntAB[1], sc->binB, sc->rB, h, ws);
  if (threadIdx.x == 0) {
    double a = (double)__uint_as_float(va);
    double b = (double)__uint_as_float(vb);
    double th = (tfrac >= 0.5) ? (b - (b - a) * (1.0 - tfrac)) : (a + (b - a) * tfrac);
    sc->thresh = (float)th;
  }
}

// ---------------- K8: masked huber + cosine reductions ---------------------------
__global__ void k_loss(const float* __restrict__ pred, const float* __restrict__ grid,
                       const float* __restrict__ tgt, const float* __restrict__ mag,
                       Scalars* sc, int n) {
  __shared__ double shH[256];
  __shared__ double shC[256];
  __shared__ int shN[256];
  __shared__ int shM[256];
  int tid = threadIdx.x;
  int i = blockIdx.x * blockDim.x + tid;
  double hub = 0.0, cs = 0.0;
  int c1 = 0, cmd = 0;
  if (i < n) {
    float th = sc->thresh;
    float m = mag[i];
    if (m <= th) {
      c1 = 1;
      float tox = __fsub_rn(tgt[3*i],   grid[3*i]);
      float toy = __fsub_rn(tgt[3*i+1], grid[3*i+1]);
      float toz = __fsub_rn(tgt[3*i+2], grid[3*i+2]);
      float px = pred[3*i], py = pred[3*i+1], pz = pred[3*i+2];
      float d0 = __fsub_rn(px, tox), d1 = __fsub_rn(py, toy), d2 = __fsub_rn(pz, toz);
      float a0 = fabsf(d0), a1 = fabsf(d1), a2 = fabsf(d2);
      float h0 = (a0 < 1.f) ? __fmul_rn(__fmul_rn(0.5f, d0), d0) : __fsub_rn(a0, 0.5f);
      float h1 = (a1 < 1.f) ? __fmul_rn(__fmul_rn(0.5f, d1), d1) : __fsub_rn(a1, 0.5f);
      float h2 = (a2 < 1.f) ? __fmul_rn(__fmul_rn(0.5f, d2), d2) : __fsub_rn(a2, 0.5f);
      hub = (double)h0 + (double)h1 + (double)h2;
      if (m > 0.f) {
        cmd = 1;
        float ps = __fadd_rn(__fadd_rn(__fmul_rn(px,px), __fmul_rn(py,py)), __fmul_rn(pz,pz));
        float pn = (ps > 0.f) ? sqrtf(ps) : 0.f;
        float dotp = __fadd_rn(__fadd_rn(__fmul_rn(px,tox), __fmul_rn(py,toy)),
                               __fmul_rn(pz,toz));
        float den = fmaxf(__fmul_rn(pn, m), 1e-4f);
        cs = (double)__fdiv_rn(dotp, den);
      }
    }
  }
  shH[tid] = hub; shC[tid] = cs; shN[tid] = c1; shM[tid] = cmd;
  __syncthreads();
  for (int off = 128; off > 0; off >>= 1) {
    if (tid < off) {
      shH[tid] += shH[tid+off];
      shC[tid] += shC[tid+off];
      shN[tid] += shN[tid+off];
      shM[tid] += shM[tid+off];
    }
    __syncthreads();
  }
  if (tid == 0) {
    atomicAdd(&sc->hub, shH[0]);
    atomicAdd(&sc->cosSum, shC[0]);
    atomicAdd(&sc->n1, shN[0]);
    atomicAdd(&sc->nmd, shM[0]);
  }
}

// ---------------- K9: finalize ---------------------------------------------------
__global__ void k_final(const Scalars* sc, float* out) {
  double n1 = (double)sc->n1;
  double l1 = (sc->n1 > 0) ? (sc->hub / fmax(n1 * 3.0, 1.0)) : 0.0;
  double nmd = (double)sc->nmd;
  double ld = (sc->nmd > 0) ? (1.0 - sc->cosSum / fmax(nmd, 1.0)) : 0.0;
  out[0] = (float)l1;
  out[1] = (float)ld;
}

extern "C" void kernel_launch(void* const* d_in, const int* in_sizes, int n_in,
                              void* d_out, int out_size, void* d_ws, size_t ws_size,
                              hipStream_t stream) {
  const float* pred  = (const float*)d_in[0];
  const float* grid  = (const float*)d_in[1];
  const int*   label = (const int*)d_in[2];
  const int*   batch = (const int*)d_in[3];
  int n = in_sizes[2];
  int nhb = (n + 1023) / 1024;
  int mstride = n / 4;   // per-code miss capacity (points/code ~ n/16; 4x margin)

  char* p = (char*)d_ws;
  auto take = [&](size_t bytes) -> char* {
    char* r = p;
    p += (bytes + 255) & ~(size_t)255;
    return r;
  };
  int*    cnt      = (int*)   take((size_t)SLOTS*4);
  float*  sx       = (float*) take((size_t)SLOTS*4);
  float*  sy       = (float*) take((size_t)SLOTS*4);
  float*  sz       = (float*) take((size_t)SLOTS*4);
  int*    lmask    = (int*)   take((size_t)SLOTS*4);
  float4* ctr      = (float4*)take((size_t)SLOTS*16);
  float4* pC       = (float4*)take((size_t)SLOTS*16);
  int*    blockCnt = (int*)   take((size_t)NBLK*NCODE*4);
  int*    blockBase= (int*)   take((size_t)NBLK*NCODE*4);
  int*    codeBase = (int*)   take(NCODE*4);
  int*    codeCnt  = (int*)   take(NCODE*4);
  int*    blCnt    = (int*)   take(16*4);
  float*  blSum    = (float*) take(48*4);
  int*    ghist    = (int*)   take((size_t)nhb*HB*4);
  unsigned* bufA   = (unsigned*)take((size_t)n*4);
  unsigned* bufB   = (unsigned*)take((size_t)n*4);
  int*    cntAB    = (int*)   take(2*4);
  float*  tgt      = (float*) take((size_t)n*3*4);
  float*  mag      = (float*) take((size_t)n*4);
  int*    missPart = (int*)   take((size_t)NCODE*mstride*4);
  int*    missCnt  = (int*)   take(NCODE*4);
  Scalars* sc      = (Scalars*)take(sizeof(Scalars));

  int nb = (n + 255) / 256;

  k_init<<<NBLK, 256, 0, stream>>>(cnt, sx, sy, sz, lmask, blCnt, blSum, cntAB,
                                   missCnt, sc);
  k_scatter<<<nb, 256, 0, stream>>>(grid, label, batch, cnt, sx, sy, sz, lmask,
                                    blCnt, blSum, n);
  k_prep<<<NBLK, 256, 0, stream>>>(cnt, sx, sy, sz, lmask, ctr, blockCnt);
  k_bases<<<1, 64, 0, stream>>>(blockCnt, blockBase, codeBase, codeCnt, sc);
  k_compact<<<NBLK, 256, 0, stream>>>(ctr, blockBase, codeBase, pC);
  k_targets<<<nb, 256, 0, stream>>>(grid, label, batch, ctr, blCnt, blSum,
                                    tgt, mag, missPart, missCnt, mstride, n);
  k_fallback<<<NCODE * FBK, 256, 0, stream>>>(grid, pC, codeBase, codeCnt,
                                              missPart, missCnt, tgt, mag, mstride);
  k_hist<<<nhb, 1024, 0, stream>>>(mag, ghist, n);

  double vi = 0.99 * (double)(n - 1);
  int r0 = (int)vi;
  int r1 = r0 + 1; if (r1 > n - 1) r1 = n - 1;
  double tfrac = vi - (double)r0;

  k_redsel<<<1, 1024, 0, stream>>>(ghist, nhb, sc, r0, r1);
  k_gather<<<nb, 256, 0, stream>>>(mag, sc, bufA, bufB, cntAB, n);
  k_sel<<<1, 1024, 0, stream>>>(bufA, bufB, cntAB, sc, tfrac);
  k_loss<<<nb, 256, 0, stream>>>(pred, grid, tgt, mag, sc, n);
  k_final<<<1, 1, 0, stream>>>(sc, (float*)d_out);
}

// Round 9
// 202.927 us; speedup vs baseline: 1.1125x; 1.1125x over previous
//
#include <hip/hip_runtime.h>
#include <climits>

#define VOXD 25
#define SLOT3 (VOXD*VOXD*VOXD)      // 15625
#define SLOTS (2*SLOT3)             // 31250
#define NCLS 8
#define NCODE 16
#define NBLK ((SLOTS + 255) / 256)  // 123
#define HB 2048                     // radix bins (11 bits)
#define FBK 64                      // fallback blocks per code
#define GSZ 16                      // threads per miss point
#define MPB (256 / GSZ)             // misses per block pass = 16

struct Scalars {
  double hub;
  double cosSum;
  int n1;
  int nmd;
  int missCount;
  int nPure;
  int binA, rA, binB, rB;
  float thresh;
  int pad;
};

__device__ __forceinline__ int voxslot(int b, int vx, int vy, int vz) {
  return ((b * VOXD + vx) * VOXD + vy) * VOXD + vz;
}

// ---- block-wide inclusive scan (int), 1024 threads = 16 waves ----
__device__ __forceinline__ int block_scan_i(int v, int* ws, int* total) {
  int lane = threadIdx.x & 63, w = threadIdx.x >> 6;
  int s = v;
  #pragma unroll
  for (int off = 1; off < 64; off <<= 1) {
    int t = __shfl_up(s, off, 64);
    if (lane >= off) s += t;
  }
  if (lane == 63) ws[w] = s;
  __syncthreads();
  if (threadIdx.x < 16) {
    int x = ws[threadIdx.x];
    #pragma unroll
    for (int off = 1; off < 16; off <<= 1) {
      int t = __shfl_up(x, off, 64);
      if (lane >= off) x += t;
    }
    ws[threadIdx.x] = x;
  }
  __syncthreads();
  if (w > 0) s += ws[w - 1];
  *total = ws[15];
  __syncthreads();
  return s;
}

// ---- 256-thread packed u64 scan (16 codes x 16-bit fields), 4 waves ----
__device__ __forceinline__ void scan4_256(unsigned long long v[4],
                                          unsigned long long* ws /*16*/) {
  int lane = threadIdx.x & 63, w = threadIdx.x >> 6;
  #pragma unroll
  for (int q = 0; q < 4; ++q) {
    unsigned long long s = v[q];
    #pragma unroll
    for (int off = 1; off < 64; off <<= 1) {
      unsigned long long t = __shfl_up(s, off, 64);
      if (lane >= off) s += t;
    }
    v[q] = s;
    if (lane == 63) ws[q * 4 + w] = s;
  }
  __syncthreads();
  if (threadIdx.x < 16) {
    int q = threadIdx.x >> 2, idx = threadIdx.x & 3;
    unsigned long long x = ws[q * 4 + idx];
    #pragma unroll
    for (int off = 1; off < 4; off <<= 1) {
      unsigned long long t = __shfl_up(x, off, 64);
      if (idx >= off) x += t;
    }
    ws[q * 4 + idx] = x;
  }
  __syncthreads();
  #pragma unroll
  for (int q = 0; q < 4; ++q) if (w > 0) v[q] += ws[q * 4 + w - 1];
}

// ---------------- K1: zero-init ----------------
__global__ void k_init(int* cnt, float* sx, float* sy, float* sz, int* lmask,
                       int* blCnt, float* blSum, int* cntAB, int* missCnt, Scalars* sc) {
  int i = blockIdx.x * blockDim.x + threadIdx.x;
  if (i < SLOTS) {
    cnt[i] = 0; sx[i] = 0.f; sy[i] = 0.f; sz[i] = 0.f; lmask[i] = 0;
  }
  if (i < 16) { blCnt[i] = 0; blSum[3*i] = 0.f; blSum[3*i+1] = 0.f; blSum[3*i+2] = 0.f; }
  if (i < NCODE) missCnt[i] = 0;
  if (i < 2) cntAB[i] = 0;
  if (i == 0) {
    sc->hub = 0.0; sc->cosSum = 0.0; sc->n1 = 0; sc->nmd = 0;
    sc->missCount = 0; sc->nPure = 0;
  }
}

// ---------------- K2: per-point scatter; label bitmask; LDS-agg (b,l) stats ------
__global__ void k_scatter(const float* __restrict__ grid, const int* __restrict__ label,
                          const int* __restrict__ batch,
                          int* cnt, float* sx, float* sy, float* sz, int* lmask,
                          int* blCnt, float* blSum, int n) {
  __shared__ int sCnt[NCODE];
  __shared__ float sSum[3 * NCODE];
  int tid = threadIdx.x;
  if (tid < NCODE) sCnt[tid] = 0;
  if (tid < 3 * NCODE) sSum[tid] = 0.f;
  __syncthreads();
  int i = blockIdx.x * blockDim.x + tid;
  if (i < n) {
    float gx = grid[3*i], gy = grid[3*i+1], gz = grid[3*i+2];
    int vx = (int)floorf(gx * (1.0f/16.0f));
    int vy = (int)floorf(gy * (1.0f/16.0f));
    int vz = (int)floorf(gz * (1.0f/16.0f));
    int b = batch[i], l = label[i];
    int s = voxslot(b, vx, vy, vz);
    atomicAdd(&cnt[s], 1);
    atomicAdd(&sx[s], gx); atomicAdd(&sy[s], gy); atomicAdd(&sz[s], gz);
    atomicOr(&lmask[s], 1 << l);
    int bl = b * NCLS + l;
    atomicAdd(&sCnt[bl], 1);
    atomicAdd(&sSum[3*bl], gx); atomicAdd(&sSum[3*bl+1], gy); atomicAdd(&sSum[3*bl+2], gz);
  }
  __syncthreads();
  if (tid < NCODE && sCnt[tid] != 0) atomicAdd(&blCnt[tid], sCnt[tid]);
  if (tid < 3 * NCODE && sSum[tid] != 0.f) atomicAdd(&blSum[tid], sSum[tid]);
}

// ---------------- K3a: consolidate slot table to float4 + per-block code counts --
__global__ void k_prep(const int* cnt, const float* sx, const float* sy, const float* sz,
                       const int* lmask, float4* ctr, int* blockCnt) {
  __shared__ int sc16[NCODE];
  if (threadIdx.x < NCODE) sc16[threadIdx.x] = 0;
  __syncthreads();
  int s = blockIdx.x * 256 + threadIdx.x;
  if (s < SLOTS) {
    int c = cnt[s];
    float4 v = make_float4(0.f, 0.f, 0.f, __int_as_float(-2));
    if (c > 0) {
      float fc = (float)c;
      float cx = __fdiv_rn(sx[s], fc);
      float cy = __fdiv_rn(sy[s], fc);
      float cz = __fdiv_rn(sz[s], fc);
      int m = lmask[s];
      bool pure = (m & (m - 1)) == 0;
      int lbl = __ffs(m) - 1;
      int meta = pure ? lbl : -1;
      v = make_float4(cx, cy, cz, __int_as_float(meta));
      if (pure) atomicAdd(&sc16[(s / SLOT3) * NCLS + lbl], 1);
    }
    ctr[s] = v;
  }
  __syncthreads();
  if (threadIdx.x < NCODE) blockCnt[blockIdx.x * NCODE + threadIdx.x] = sc16[threadIdx.x];
}

// ---------------- K3b: bases per (block,code) and per code -----------------------
__global__ void k_bases(const int* blockCnt, int* blockBase, int* codeBase,
                        int* codeCnt, Scalars* sc) {
  __shared__ int tot[NCODE];
  int c = threadIdx.x;
  if (c < NCODE) {
    int run = 0;
    for (int b = 0; b < NBLK; ++b) {
      blockBase[b * NCODE + c] = run;
      run += blockCnt[b * NCODE + c];
    }
    tot[c] = run;
  }
  __syncthreads();
  if (c == 0) {
    int cum = 0;
    for (int k = 0; k < NCODE; ++k) { codeBase[k] = cum; codeCnt[k] = tot[k]; cum += tot[k]; }
    sc->nPure = cum;
  }
}

// ---------------- K4: compact pure clusters into per-code buckets (float4) -------
__global__ void k_compact(const float4* __restrict__ ctr,
                          const int* blockBase, const int* codeBase, float4* pC) {
  __shared__ unsigned long long ws[16];
  int s = blockIdx.x * 256 + threadIdx.x;
  int f = 0, code = 0;
  float4 cv = make_float4(0.f, 0.f, 0.f, 0.f);
  if (s < SLOTS) {
    cv = ctr[s];
    int meta = __float_as_int(cv.w);
    if (meta >= 0) { f = 1; code = (s / SLOT3) * NCLS + meta; }
  }
  unsigned long long v[4] = {0ULL, 0ULL, 0ULL, 0ULL};
  if (f) v[code >> 2] = 1ULL << (16 * (code & 3));
  scan4_256(v, ws);
  if (f) {
    int rank = (int)((v[code >> 2] >> (16 * (code & 3))) & 0xFFFFULL) - 1;
    int pos = codeBase[code] + blockBase[blockIdx.x * NCODE + code] + rank;
    float c2 = __fadd_rn(__fadd_rn(__fmul_rn(cv.x,cv.x), __fmul_rn(cv.y,cv.y)),
                         __fmul_rn(cv.z,cv.z));
    pC[pos] = make_float4(cv.x, cv.y, cv.z, c2);
  }
}

// ---------------- K5: probe targets + per-code block-aggregated miss lists -------
__global__ void k_targets(const float* __restrict__ grid, const int* __restrict__ label,
                          const int* __restrict__ batch,
                          const float4* __restrict__ ctr,
                          const int* __restrict__ blCnt, const float* __restrict__ blSum,
                          float* tgt, float* mag,
                          int* missPart, int* missCnt, int mstride, int n) {
  __shared__ int wCnt[4][NCODE];
  __shared__ int gBase[NCODE];
  int tid = threadIdx.x, lane = tid & 63, w = tid >> 6;
  int i = blockIdx.x * blockDim.x + tid;
  bool active = (i < n);
  bool miss = false;
  int mcode = -1;

  if (active) {
    float gx = grid[3*i], gy = grid[3*i+1], gz = grid[3*i+2];
    int vx = (int)floorf(gx * (1.0f/16.0f));
    int vy = (int)floorf(gy * (1.0f/16.0f));
    int vz = (int)floorf(gz * (1.0f/16.0f));
    int b = batch[i], l = label[i];
    int s = voxslot(b, vx, vy, vz);

    float4 own = ctr[s];
    bool purept = (__float_as_int(own.w) >= 0);

    int bl = b * NCLS + l;
    float fbc = (float)max(blCnt[bl], 1);
    float gcx = __fdiv_rn(blSum[3*bl],   fbc);
    float gcy = __fdiv_rn(blSum[3*bl+1], fbc);
    float gcz = __fdiv_rn(blSum[3*bl+2], fbc);

    float dx = __fsub_rn(gcx, own.x);
    float dy = __fsub_rn(gcy, own.y);
    float dz = __fsub_rn(gcz, own.z);
    int sgx = (dx > 0.f) ? 1 : ((dx < 0.f) ? -1 : 0);
    int sgy = (dy > 0.f) ? 1 : ((dy < 0.f) ? -1 : 0);
    int sgz = (dz > 0.f) ? 1 : ((dz < 0.f) ? -1 : 0);

    int ax1 = vx + sgx,     ay1 = vy + sgy,     az1 = vz + sgz;
    int ax2 = vx + 2 * sgx, ay2 = vy + 2 * sgy, az2 = vz + 2 * sgz;
    bool v1 = (unsigned)ax1 < (unsigned)VOXD && (unsigned)ay1 < (unsigned)VOXD &&
              (unsigned)az1 < (unsigned)VOXD;
    bool v2 = (unsigned)ax2 < (unsigned)VOXD && (unsigned)ay2 < (unsigned)VOXD &&
              (unsigned)az2 < (unsigned)VOXD;

    float4 q1 = make_float4(0.f, 0.f, 0.f, __int_as_float(-3));
    float4 q2 = q1;
    if (v1) q1 = ctr[voxslot(b, ax1, ay1, az1)];
    if (v2) q2 = ctr[voxslot(b, ax2, ay2, az2)];

    bool hit1 = v1 && (__float_as_int(q1.w) == l);
    bool hit2 = v2 && (__float_as_int(q2.w) == l);
    bool hit = hit1 || hit2;

    float tx = hit1 ? q1.x : (hit2 ? q2.x : gx);
    float ty = hit1 ? q1.y : (hit2 ? q2.y : gy);
    float tz = hit1 ? q1.z : (hit2 ? q2.z : gz);

    tgt[3*i] = tx; tgt[3*i+1] = ty; tgt[3*i+2] = tz;
    miss = (!purept && !hit);
    if (miss) {
      mcode = bl;
    } else {
      float tox = __fsub_rn(tx, gx), toy = __fsub_rn(ty, gy), toz = __fsub_rn(tz, gz);
      float ssq = __fadd_rn(__fadd_rn(__fmul_rn(tox,tox), __fmul_rn(toy,toy)),
                            __fmul_rn(toz,toz));
      float m = (ssq > 0.f) ? sqrtf(ssq) : 0.f;
      mag[i] = m;
    }
  }
  // per-wave per-code counts + in-wave rank
  int myrank = 0;
  #pragma unroll
  for (int c = 0; c < NCODE; ++c) {
    unsigned long long mb = __ballot(mcode == c);
    if (lane == 0) wCnt[w][c] = __popcll(mb);
    if (mcode == c) myrank = __popcll(mb & ((1ULL << lane) - 1ULL));
  }
  __syncthreads();
  if (tid < NCODE) {
    int tot = wCnt[0][tid] + wCnt[1][tid] + wCnt[2][tid] + wCnt[3][tid];
    gBase[tid] = (tot > 0) ? atomicAdd(&missCnt[tid], tot) : 0;
  }
  __syncthreads();
  if (miss) {
    int base = gBase[mcode];
    for (int q = 0; q < 4; ++q) if (q < w) base += wCnt[q][mcode];
    missPart[mcode * mstride + base + myrank] = i;
  }
}

// ---------------- K6: fallback — 16-thread group per miss, LDS tiles -------------
__global__ void __launch_bounds__(256) k_fallback(
    const float* __restrict__ grid,
    const float4* __restrict__ pC,
    const int* __restrict__ codeBase, const int* __restrict__ codeCnt,
    const int* __restrict__ missPart, const int* __restrict__ missCnt,
    float* tgt, float* mag, int mstride) {
  __shared__ float4 tile[1024];
  int c = blockIdx.x / FBK;
  int y = blockIdx.x % FBK;
  int mc = missCnt[c];
  if (y * MPB >= mc) return;           // uniform per block
  int cc = codeCnt[c];
  int j0 = codeBase[c];
  const int* mlist = missPart + c * mstride;
  int g = threadIdx.x >> 4;            // group 0..15
  int q = threadIdx.x & (GSZ - 1);     // lane in group

  for (int base = y * MPB; base < mc; base += FBK * MPB) {
    int t = base + g;
    bool valid = (t < mc);
    int idx = 0;
    float gx = 0.f, gy = 0.f, gz = 0.f, p2 = 0.f;
    if (valid) {
      idx = mlist[t];
      gx = grid[3*idx]; gy = grid[3*idx+1]; gz = grid[3*idx+2];
      p2 = __fadd_rn(__fadd_rn(__fmul_rn(gx,gx), __fmul_rn(gy,gy)), __fmul_rn(gz,gz));
    }
    unsigned long long key = 0xFFFFFFFFFFFFFFFFULL;
    for (int tb = 0; tb < cc; tb += 1024) {
      int m = min(1024, cc - tb);
      __syncthreads();
      for (int j = threadIdx.x; j < m; j += 256) tile[j] = pC[j0 + tb + j];
      __syncthreads();
      if (valid) {
        for (int j = q; j < m; j += GSZ) {
          float4 cl = tile[j];
          float dot = __fadd_rn(__fadd_rn(__fmul_rn(gx,cl.x), __fmul_rn(gy,cl.y)),
                                __fmul_rn(gz,cl.z));
          float d2 = __fadd_rn(__fsub_rn(p2, __fmul_rn(2.0f, dot)), cl.w);
          unsigned fb = __float_as_uint(d2);
          fb = (fb >> 31) ? ~fb : (fb | 0x80000000u);
          unsigned long long k2 = ((unsigned long long)fb << 32) | (unsigned)(tb + j);
          if (k2 < key) key = k2;
        }
      }
    }
    // group (16-lane) lexicographic (d2, j) min; xor masks < 16 stay in-group
    #pragma unroll
    for (int off = 1; off < GSZ; off <<= 1) {
      unsigned long long o = __shfl_xor(key, off, 64);
      if (o < key) key = o;
    }
    if (valid && q == 0) {
      if (cc > 0) {
        int bj = (int)(unsigned)(key & 0xFFFFFFFFULL);
        float4 cl = pC[j0 + bj];
        tgt[3*idx] = cl.x; tgt[3*idx+1] = cl.y; tgt[3*idx+2] = cl.z;
        float tox = __fsub_rn(cl.x, gx), toy = __fsub_rn(cl.y, gy), toz = __fsub_rn(cl.z, gz);
        float ssq = __fadd_rn(__fadd_rn(__fmul_rn(tox,tox), __fmul_rn(toy,toy)),
                              __fmul_rn(toz,toz));
        mag[idx] = (ssq > 0.f) ? sqrtf(ssq) : 0.f;
      } else {
        mag[idx] = 0.f;
      }
    }
    __syncthreads();
  }
}

// ---------------- K7a: LDS-private coarse histogram (bits >> 21), no atomics -----
__global__ void __launch_bounds__(1024) k_hist(const float* __restrict__ mag,
                                               int* ghist, int n) {
  __shared__ int h[HB];
  for (int t = threadIdx.x; t < HB; t += 1024) h[t] = 0;
  __syncthreads();
  int i = blockIdx.x * 1024 + threadIdx.x;
  if (i < n) atomicAdd(&h[__float_as_uint(mag[i]) >> 21], 1);
  __syncthreads();
  for (int t = threadIdx.x; t < HB; t += 1024)
    ghist[blockIdx.x * HB + t] = h[t];
}

// ---------------- K7b: reduce block hists + find coarse bins of r0, r1 -----------
__global__ void __launch_bounds__(1024) k_redsel(const int* __restrict__ ghist, int nhb,
                                                 Scalars* sc, int r0, int r1) {
  __shared__ int ws[16];
  __shared__ int sBinA, sRA, sBinB, sRB;
  int t = threadIdx.x;
  int s0 = 0, s1 = 0;
  for (int b = 0; b < nhb; ++b) {
    int2 v = ((const int2*)(ghist + b * HB))[t];
    s0 += v.x; s1 += v.y;
  }
  int tot;
  int incl = block_scan_i(s0 + s1, ws, &tot);
  int b1 = incl - s1, b0 = b1 - s0;
  if (r0 >= b0 && r0 < b0 + s0) { sBinA = 2*t;   sRA = r0 - b0; }
  if (r0 >= b1 && r0 < b1 + s1) { sBinA = 2*t+1; sRA = r0 - b1; }
  if (r1 >= b0 && r1 < b0 + s0) { sBinB = 2*t;   sRB = r1 - b0; }
  if (r1 >= b1 && r1 < b1 + s1) { sBinB = 2*t+1; sRB = r1 - b1; }
  __syncthreads();
  if (t == 0) { sc->binA = sBinA; sc->rA = sRA; sc->binB = sBinB; sc->rB = sRB; }
}

// ---------------- K7c: gather candidate bit-patterns for the two coarse bins -----
__global__ void k_gather(const float* __restrict__ mag, const Scalars* sc,
                         unsigned* bufA, unsigned* bufB, int* cntAB, int n) {
  int i = blockIdx.x * blockDim.x + threadIdx.x;
  int lane = threadIdx.x & 63;
  unsigned bits = 0;
  bool inA = false, inB = false;
  if (i < n) {
    bits = __float_as_uint(mag[i]);
    unsigned c = bits >> 21;
    inA = (c == (unsigned)sc->binA);
    inB = (c == (unsigned)sc->binB);
  }
  {
    unsigned long long mb = __ballot(inA);
    int mc = __popcll(mb);
    int base = 0;
    if (lane == 0 && mc > 0) base = atomicAdd(&cntAB[0], mc);
    base = __shfl(base, 0, 64);
    if (inA) bufA[base + __popcll(mb & ((1ULL << lane) - 1ULL))] = bits;
  }
  {
    unsigned long long mb = __ballot(inB);
    int mc = __popcll(mb);
    int base = 0;
    if (lane == 0 && mc > 0) base = atomicAdd(&cntAB[1], mc);
    base = __shfl(base, 0, 64);
    if (inB) bufB[base + __popcll(mb & ((1ULL << lane) - 1ULL))] = bits;
  }
}

// ---------------- K7d helper: exact rank select within a coarse bin --------------
__device__ unsigned select_in_bin(const unsigned* __restrict__ buf, int cnt,
                                  int coarse, int rank, int* h, int* ws) {
  __shared__ int sSub, sSubR, sLow;
  for (int t = threadIdx.x; t < HB; t += 1024) h[t] = 0;
  __syncthreads();
  for (int t = threadIdx.x; t < cnt; t += 1024)
    atomicAdd(&h[(buf[t] >> 10) & 0x7FF], 1);
  __syncthreads();
  int t = threadIdx.x;
  int s0 = h[2*t], s1 = h[2*t+1];
  int tot;
  int incl = block_scan_i(s0 + s1, ws, &tot);
  int b1 = incl - s1, b0 = b1 - s0;
  if (rank >= b0 && rank < b0 + s0) { sSub = 2*t;   sSubR = rank - b0; }
  if (rank >= b1 && rank < b1 + s1) { sSub = 2*t+1; sSubR = rank - b1; }
  __syncthreads();
  int subv = sSub, subr = sSubR;
  h[t] = 0;
  __syncthreads();
  for (int q = threadIdx.x; q < cnt; q += 1024) {
    unsigned v = buf[q];
    if ((int)((v >> 10) & 0x7FF) == subv) atomicAdd(&h[v & 0x3FF], 1);
  }
  __syncthreads();
  int c = h[t];
  int tot2;
  int incl2 = block_scan_i(c, ws, &tot2);
  int lb = incl2 - c;
  if (subr >= lb && subr < lb + c) sLow = t;
  __syncthreads();
  return ((unsigned)coarse << 21) | ((unsigned)subv << 10) | (unsigned)sLow;
}

// ---------------- K7d: exact order statistics + lerp (numpy branch) --------------
__global__ void __launch_bounds__(1024) k_sel(const unsigned* __restrict__ bufA,
                                              const unsigned* __restrict__ bufB,
                                              const int* __restrict__ cntAB,
                                              Scalars* sc, double tfrac) {
  __shared__ int h[HB];
  __shared__ int ws[16];
  unsigned va = select_in_bin(bufA, cntAB[0], sc->binA, sc->rA, h, ws);
  __syncthreads();
  unsigned vb = select_in_bin(bufB, cntAB[1], sc->binB, sc->rB, h, ws);
  if (threadIdx.x == 0) {
    double a = (double)__uint_as_float(va);
    double b = (double)__uint_as_float(vb);
    double th = (tfrac >= 0.5) ? (b - (b - a) * (1.0 - tfrac)) : (a + (b - a) * tfrac);
    sc->thresh = (float)th;
  }
}

// ---------------- K8: masked huber + cosine reductions ---------------------------
__global__ void k_loss(const float* __restrict__ pred, const float* __restrict__ grid,
                       const float* __restrict__ tgt, const float* __restrict__ mag,
                       Scalars* sc, int n) {
  __shared__ double shH[256];
  __shared__ double shC[256];
  __shared__ int shN[256];
  __shared__ int shM[256];
  int tid = threadIdx.x;
  int i = blockIdx.x * blockDim.x + tid;
  double hub = 0.0, cs = 0.0;
  int c1 = 0, cmd = 0;
  if (i < n) {
    float th = sc->thresh;
    float m = mag[i];
    if (m <= th) {
      c1 = 1;
      float tox = __fsub_rn(tgt[3*i],   grid[3*i]);
      float toy = __fsub_rn(tgt[3*i+1], grid[3*i+1]);
      float toz = __fsub_rn(tgt[3*i+2], grid[3*i+2]);
      float px = pred[3*i], py = pred[3*i+1], pz = pred[3*i+2];
      float d0 = __fsub_rn(px, tox), d1 = __fsub_rn(py, toy), d2 = __fsub_rn(pz, toz);
      float a0 = fabsf(d0), a1 = fabsf(d1), a2 = fabsf(d2);
      float h0 = (a0 < 1.f) ? __fmul_rn(__fmul_rn(0.5f, d0), d0) : __fsub_rn(a0, 0.5f);
      float h1 = (a1 < 1.f) ? __fmul_rn(__fmul_rn(0.5f, d1), d1) : __fsub_rn(a1, 0.5f);
      float h2 = (a2 < 1.f) ? __fmul_rn(__fmul_rn(0.5f, d2), d2) : __fsub_rn(a2, 0.5f);
      hub = (double)h0 + (double)h1 + (double)h2;
      if (m > 0.f) {
        cmd = 1;
        float ps = __fadd_rn(__fadd_rn(__fmul_rn(px,px), __fmul_rn(py,py)), __fmul_rn(pz,pz));
        float pn = (ps > 0.f) ? sqrtf(ps) : 0.f;
        float dotp = __fadd_rn(__fadd_rn(__fmul_rn(px,tox), __fmul_rn(py,toy)),
                               __fmul_rn(pz,toz));
        float den = fmaxf(__fmul_rn(pn, m), 1e-4f);
        cs = (double)__fdiv_rn(dotp, den);
      }
    }
  }
  shH[tid] = hub; shC[tid] = cs; shN[tid] = c1; shM[tid] = cmd;
  __syncthreads();
  for (int off = 128; off > 0; off >>= 1) {
    if (tid < off) {
      shH[tid] += shH[tid+off];
      shC[tid] += shC[tid+off];
      shN[tid] += shN[tid+off];
      shM[tid] += shM[tid+off];
    }
    __syncthreads();
  }
  if (tid == 0) {
    atomicAdd(&sc->hub, shH[0]);
    atomicAdd(&sc->cosSum, shC[0]);
    atomicAdd(&sc->n1, shN[0]);
    atomicAdd(&sc->nmd, shM[0]);
  }
}

// ---------------- K9: finalize ---------------------------------------------------
__global__ void k_final(const Scalars* sc, float* out) {
  double n1 = (double)sc->n1;
  double l1 = (sc->n1 > 0) ? (sc->hub / fmax(n1 * 3.0, 1.0)) : 0.0;
  double nmd = (double)sc->nmd;
  double ld = (sc->nmd > 0) ? (1.0 - sc->cosSum / fmax(nmd, 1.0)) : 0.0;
  out[0] = (float)l1;
  out[1] = (float)ld;
}

extern "C" void kernel_launch(void* const* d_in, const int* in_sizes, int n_in,
                              void* d_out, int out_size, void* d_ws, size_t ws_size,
                              hipStream_t stream) {
  const float* pred  = (const float*)d_in[0];
  const float* grid  = (const float*)d_in[1];
  const int*   label = (const int*)d_in[2];
  const int*   batch = (const int*)d_in[3];
  int n = in_sizes[2];
  int nhb = (n + 1023) / 1024;
  int mstride = n / 4;   // per-code miss capacity (points/code ~ n/16; 4x margin)

  char* p = (char*)d_ws;
  auto take = [&](size_t bytes) -> char* {
    char* r = p;
    p += (bytes + 255) & ~(size_t)255;
    return r;
  };
  int*    cnt      = (int*)   take((size_t)SLOTS*4);
  float*  sx       = (float*) take((size_t)SLOTS*4);
  float*  sy       = (float*) take((size_t)SLOTS*4);
  float*  sz       = (float*) take((size_t)SLOTS*4);
  int*    lmask    = (int*)   take((size_t)SLOTS*4);
  float4* ctr      = (float4*)take((size_t)SLOTS*16);
  float4* pC       = (float4*)take((size_t)SLOTS*16);
  int*    blockCnt = (int*)   take((size_t)NBLK*NCODE*4);
  int*    blockBase= (int*)   take((size_t)NBLK*NCODE*4);
  int*    codeBase = (int*)   take(NCODE*4);
  int*    codeCnt  = (int*)   take(NCODE*4);
  int*    blCnt    = (int*)   take(16*4);
  float*  blSum    = (float*) take(48*4);
  int*    ghist    = (int*)   take((size_t)nhb*HB*4);
  unsigned* bufA   = (unsigned*)take((size_t)n*4);
  unsigned* bufB   = (unsigned*)take((size_t)n*4);
  int*    cntAB    = (int*)   take(2*4);
  float*  tgt      = (float*) take((size_t)n*3*4);
  float*  mag      = (float*) take((size_t)n*4);
  int*    missPart = (int*)   take((size_t)NCODE*mstride*4);
  int*    missCnt  = (int*)   take(NCODE*4);
  Scalars* sc      = (Scalars*)take(sizeof(Scalars));

  int nb = (n + 255) / 256;

  k_init<<<NBLK, 256, 0, stream>>>(cnt, sx, sy, sz, lmask, blCnt, blSum, cntAB,
                                   missCnt, sc);
  k_scatter<<<nb, 256, 0, stream>>>(grid, label, batch, cnt, sx, sy, sz, lmask,
                                    blCnt, blSum, n);
  k_prep<<<NBLK, 256, 0, stream>>>(cnt, sx, sy, sz, lmask, ctr, blockCnt);
  k_bases<<<1, 64, 0, stream>>>(blockCnt, blockBase, codeBase, codeCnt, sc);
  k_compact<<<NBLK, 256, 0, stream>>>(ctr, blockBase, codeBase, pC);
  k_targets<<<nb, 256, 0, stream>>>(grid, label, batch, ctr, blCnt, blSum,
                                    tgt, mag, missPart, missCnt, mstride, n);
  k_fallback<<<NCODE * FBK, 256, 0, stream>>>(grid, pC, codeBase, codeCnt,
                                              missPart, missCnt, tgt, mag, mstride);
  k_hist<<<nhb, 1024, 0, stream>>>(mag, ghist, n);

  double vi = 0.99 * (double)(n - 1);
  int r0 = (int)vi;
  int r1 = r0 + 1; if (r1 > n - 1) r1 = n - 1;
  double tfrac = vi - (double)r0;

  k_redsel<<<1, 1024, 0, stream>>>(ghist, nhb, sc, r0, r1);
  k_gather<<<nb, 256, 0, stream>>>(mag, sc, bufA, bufB, cntAB, n);
  k_sel<<<1, 1024, 0, stream>>>(bufA, bufB, cntAB, sc, tfrac);
  k_loss<<<nb, 256, 0, stream>>>(pred, grid, tgt, mag, sc, n);
  k_final<<<1, 1, 0, stream>>>(sc, (float*)d_out);
}

// Round 10
// 168.953 us; speedup vs baseline: 1.3362x; 1.2011x over previous
//
#include <hip/hip_runtime.h>
#include <climits>

#define VOXD 25
#define SLOT3 (VOXD*VOXD*VOXD)      // 15625
#define SLOTS (2*SLOT3)             // 31250
#define NCLS 8
#define NCODE 16
#define NBLK ((SLOTS + 255) / 256)  // 123
#define HB 2048                     // radix bins (11 bits)
#define FBK 64                      // fallback blocks per code
#define GSZ 16                      // threads per miss point
#define MPB (256 / GSZ)             // misses per block pass = 16
#define CSTRIDE SLOT3               // per-code bucket capacity

struct Scalars {
  double hub;
  double cosSum;
  int n1;
  int nmd;
  int binA, rA, binB, rB;
  float thresh;
  int pad;
};

__device__ __forceinline__ int voxslot(int b, int vx, int vy, int vz) {
  return ((b * VOXD + vx) * VOXD + vy) * VOXD + vz;
}

// ---- block-wide inclusive scan (int), 1024 threads = 16 waves ----
__device__ __forceinline__ int block_scan_i(int v, int* ws, int* total) {
  int lane = threadIdx.x & 63, w = threadIdx.x >> 6;
  int s = v;
  #pragma unroll
  for (int off = 1; off < 64; off <<= 1) {
    int t = __shfl_up(s, off, 64);
    if (lane >= off) s += t;
  }
  if (lane == 63) ws[w] = s;
  __syncthreads();
  if (threadIdx.x < 16) {
    int x = ws[threadIdx.x];
    #pragma unroll
    for (int off = 1; off < 16; off <<= 1) {
      int t = __shfl_up(x, off, 64);
      if (lane >= off) x += t;
    }
    ws[threadIdx.x] = x;
  }
  __syncthreads();
  if (w > 0) s += ws[w - 1];
  *total = ws[15];
  __syncthreads();
  return s;
}

// ---------------- K2: per-point scatter; label bitmask; LDS-agg (b,l) stats ------
__global__ void k_scatter(const float* __restrict__ grid, const int* __restrict__ label,
                          const int* __restrict__ batch,
                          int* cnt, float* sx, float* sy, float* sz, int* lmask,
                          int* blCnt, float* blSum, int n) {
  __shared__ int sCnt[NCODE];
  __shared__ float sSum[3 * NCODE];
  int tid = threadIdx.x;
  if (tid < NCODE) sCnt[tid] = 0;
  if (tid < 3 * NCODE) sSum[tid] = 0.f;
  __syncthreads();
  int i = blockIdx.x * blockDim.x + tid;
  if (i < n) {
    float gx = grid[3*i], gy = grid[3*i+1], gz = grid[3*i+2];
    int vx = (int)floorf(gx * (1.0f/16.0f));
    int vy = (int)floorf(gy * (1.0f/16.0f));
    int vz = (int)floorf(gz * (1.0f/16.0f));
    int b = batch[i], l = label[i];
    int s = voxslot(b, vx, vy, vz);
    atomicAdd(&cnt[s], 1);
    atomicAdd(&sx[s], gx); atomicAdd(&sy[s], gy); atomicAdd(&sz[s], gz);
    atomicOr(&lmask[s], 1 << l);
    int bl = b * NCLS + l;
    atomicAdd(&sCnt[bl], 1);
    atomicAdd(&sSum[3*bl], gx); atomicAdd(&sSum[3*bl+1], gy); atomicAdd(&sSum[3*bl+2], gz);
  }
  __syncthreads();
  if (tid < NCODE && sCnt[tid] != 0) atomicAdd(&blCnt[tid], sCnt[tid]);
  if (tid < 3 * NCODE && sSum[tid] != 0.f) atomicAdd(&blSum[tid], sSum[tid]);
}

// ---------------- K3: slot table float4 + direct per-code bucket append ----------
// ctr[s] = {cx, cy, cz, meta}; meta = label if pure, -1 mixed, -2 empty.
// Pure clusters appended (any order) to pC/pSlot[code*CSTRIDE + pos]; tie-breaks
// in fallback use the slot index, so bucket order is irrelevant.
__global__ void k_prep(const int* cnt, const float* sx, const float* sy, const float* sz,
                       const int* lmask, float4* ctr, float4* pC, int* pSlot,
                       int* codeCnt) {
  __shared__ int lc[NCODE];
  __shared__ int lb[NCODE];
  int tid = threadIdx.x;
  if (tid < NCODE) lc[tid] = 0;
  __syncthreads();
  int s = blockIdx.x * 256 + tid;
  int code = -1, lpos = 0;
  float4 v = make_float4(0.f, 0.f, 0.f, __int_as_float(-2));
  if (s < SLOTS) {
    int c = cnt[s];
    if (c > 0) {
      float fc = (float)c;
      float cx = __fdiv_rn(sx[s], fc);
      float cy = __fdiv_rn(sy[s], fc);
      float cz = __fdiv_rn(sz[s], fc);
      int m = lmask[s];
      bool pure = (m & (m - 1)) == 0;
      int lbl = __ffs(m) - 1;
      v = make_float4(cx, cy, cz, __int_as_float(pure ? lbl : -1));
      if (pure) {
        code = (s / SLOT3) * NCLS + lbl;
        lpos = atomicAdd(&lc[code], 1);
      }
    }
    ctr[s] = v;
  }
  __syncthreads();
  if (tid < NCODE) lb[tid] = (lc[tid] > 0) ? atomicAdd(&codeCnt[tid], lc[tid]) : 0;
  __syncthreads();
  if (code >= 0) {
    int pos = code * CSTRIDE + lb[code] + lpos;
    float c2 = __fadd_rn(__fadd_rn(__fmul_rn(v.x,v.x), __fmul_rn(v.y,v.y)),
                         __fmul_rn(v.z,v.z));
    pC[pos] = make_float4(v.x, v.y, v.z, c2);
    pSlot[pos] = s;
  }
}

// ---------------- K5: probe targets + per-code miss lists + LDS hist -------------
__global__ void k_targets(const float* __restrict__ grid, const int* __restrict__ label,
                          const int* __restrict__ batch,
                          const float4* __restrict__ ctr,
                          const int* __restrict__ blCnt, const float* __restrict__ blSum,
                          float* tgt, float* mag, int* ghist,
                          int* missPart, int* missCnt, int mstride, int n) {
  __shared__ int wCnt[4][NCODE];
  __shared__ int gBase[NCODE];
  __shared__ int h[HB];
  int tid = threadIdx.x, lane = tid & 63, w = tid >> 6;
  for (int t = tid; t < HB; t += 256) h[t] = 0;
  __syncthreads();
  int i = blockIdx.x * blockDim.x + tid;
  bool active = (i < n);
  bool miss = false;
  int mcode = -1;

  if (active) {
    float gx = grid[3*i], gy = grid[3*i+1], gz = grid[3*i+2];
    int vx = (int)floorf(gx * (1.0f/16.0f));
    int vy = (int)floorf(gy * (1.0f/16.0f));
    int vz = (int)floorf(gz * (1.0f/16.0f));
    int b = batch[i], l = label[i];
    int s = voxslot(b, vx, vy, vz);

    float4 own = ctr[s];
    bool purept = (__float_as_int(own.w) >= 0);

    int bl = b * NCLS + l;
    float fbc = (float)max(blCnt[bl], 1);
    float gcx = __fdiv_rn(blSum[3*bl],   fbc);
    float gcy = __fdiv_rn(blSum[3*bl+1], fbc);
    float gcz = __fdiv_rn(blSum[3*bl+2], fbc);

    float dx = __fsub_rn(gcx, own.x);
    float dy = __fsub_rn(gcy, own.y);
    float dz = __fsub_rn(gcz, own.z);
    int sgx = (dx > 0.f) ? 1 : ((dx < 0.f) ? -1 : 0);
    int sgy = (dy > 0.f) ? 1 : ((dy < 0.f) ? -1 : 0);
    int sgz = (dz > 0.f) ? 1 : ((dz < 0.f) ? -1 : 0);

    int ax1 = vx + sgx,     ay1 = vy + sgy,     az1 = vz + sgz;
    int ax2 = vx + 2 * sgx, ay2 = vy + 2 * sgy, az2 = vz + 2 * sgz;
    bool v1 = (unsigned)ax1 < (unsigned)VOXD && (unsigned)ay1 < (unsigned)VOXD &&
              (unsigned)az1 < (unsigned)VOXD;
    bool v2 = (unsigned)ax2 < (unsigned)VOXD && (unsigned)ay2 < (unsigned)VOXD &&
              (unsigned)az2 < (unsigned)VOXD;

    float4 q1 = make_float4(0.f, 0.f, 0.f, __int_as_float(-3));
    float4 q2 = q1;
    if (v1) q1 = ctr[voxslot(b, ax1, ay1, az1)];
    if (v2) q2 = ctr[voxslot(b, ax2, ay2, az2)];

    bool hit1 = v1 && (__float_as_int(q1.w) == l);
    bool hit2 = v2 && (__float_as_int(q2.w) == l);
    bool hit = hit1 || hit2;

    float tx = hit1 ? q1.x : (hit2 ? q2.x : gx);
    float ty = hit1 ? q1.y : (hit2 ? q2.y : gy);
    float tz = hit1 ? q1.z : (hit2 ? q2.z : gz);

    tgt[3*i] = tx; tgt[3*i+1] = ty; tgt[3*i+2] = tz;
    miss = (!purept && !hit);
    if (miss) {
      mcode = bl;
    } else {
      float tox = __fsub_rn(tx, gx), toy = __fsub_rn(ty, gy), toz = __fsub_rn(tz, gz);
      float ssq = __fadd_rn(__fadd_rn(__fmul_rn(tox,tox), __fmul_rn(toy,toy)),
                            __fmul_rn(toz,toz));
      float m = (ssq > 0.f) ? sqrtf(ssq) : 0.f;
      mag[i] = m;
      atomicAdd(&h[__float_as_uint(m) >> 21], 1);
    }
  }
  // per-wave per-code counts + in-wave rank
  int myrank = 0;
  #pragma unroll
  for (int c = 0; c < NCODE; ++c) {
    unsigned long long mb = __ballot(mcode == c);
    if (lane == 0) wCnt[w][c] = __popcll(mb);
    if (mcode == c) myrank = __popcll(mb & ((1ULL << lane) - 1ULL));
  }
  __syncthreads();
  if (tid < NCODE) {
    int tot = wCnt[0][tid] + wCnt[1][tid] + wCnt[2][tid] + wCnt[3][tid];
    gBase[tid] = (tot > 0) ? atomicAdd(&missCnt[tid], tot) : 0;
  }
  __syncthreads();
  if (miss) {
    int base = gBase[mcode];
    for (int q = 0; q < 4; ++q) if (q < w) base += wCnt[q][mcode];
    missPart[mcode * mstride + base + myrank] = i;
  }
  // flush block-private hist (aggregated: <= 1 atomic per nonzero bin per block)
  for (int t = tid; t < HB; t += 256) {
    int c = h[t];
    if (c != 0) atomicAdd(&ghist[t], c);
  }
}

// ---------------- K6: fallback — 16-thread group per miss, LDS tiles + hist ------
__global__ void __launch_bounds__(256) k_fallback(
    const float* __restrict__ grid,
    const float4* __restrict__ pC, const int* __restrict__ pSlot,
    const float4* __restrict__ ctr,
    const int* __restrict__ codeCnt,
    const int* __restrict__ missPart, const int* __restrict__ missCnt,
    float* tgt, float* mag, int* ghist, int mstride) {
  __shared__ float4 tile[1024];
  __shared__ int stile[1024];
  __shared__ int h[HB];
  int c = blockIdx.x / FBK;
  int y = blockIdx.x % FBK;
  int mc = missCnt[c];
  if (y * MPB >= mc) return;           // uniform per block
  int cc = codeCnt[c];
  int j0 = c * CSTRIDE;
  const int* mlist = missPart + c * mstride;
  int g = threadIdx.x >> 4;            // group 0..15
  int q = threadIdx.x & (GSZ - 1);     // lane in group
  for (int t = threadIdx.x; t < HB; t += 256) h[t] = 0;

  for (int base = y * MPB; base < mc; base += FBK * MPB) {
    int t = base + g;
    bool valid = (t < mc);
    int idx = 0;
    float gx = 0.f, gy = 0.f, gz = 0.f, p2 = 0.f;
    if (valid) {
      idx = mlist[t];
      gx = grid[3*idx]; gy = grid[3*idx+1]; gz = grid[3*idx+2];
      p2 = __fadd_rn(__fadd_rn(__fmul_rn(gx,gx), __fmul_rn(gy,gy)), __fmul_rn(gz,gz));
    }
    unsigned long long key = 0xFFFFFFFFFFFFFFFFULL;
    for (int tb = 0; tb < cc; tb += 1024) {
      int m = min(1024, cc - tb);
      __syncthreads();
      for (int j = threadIdx.x; j < m; j += 256) {
        tile[j] = pC[j0 + tb + j];
        stile[j] = pSlot[j0 + tb + j];
      }
      __syncthreads();
      if (valid) {
        for (int j = q; j < m; j += GSZ) {
          float4 cl = tile[j];
          float dot = __fadd_rn(__fadd_rn(__fmul_rn(gx,cl.x), __fmul_rn(gy,cl.y)),
                                __fmul_rn(gz,cl.z));
          float d2 = __fadd_rn(__fsub_rn(p2, __fmul_rn(2.0f, dot)), cl.w);
          unsigned fb = __float_as_uint(d2);
          fb = (fb >> 31) ? ~fb : (fb | 0x80000000u);
          unsigned long long k2 = ((unsigned long long)fb << 32) | (unsigned)stile[j];
          if (k2 < key) key = k2;
        }
      }
    }
    // group (16-lane) lexicographic (d2, slot) min — slot order == cluster rank
    #pragma unroll
    for (int off = 1; off < GSZ; off <<= 1) {
      unsigned long long o = __shfl_xor(key, off, 64);
      if (o < key) key = o;
    }
    if (valid && q == 0) {
      float m = 0.f;
      if (cc > 0) {
        int slot = (int)(unsigned)(key & 0xFFFFFFFFULL);
        float4 cl = ctr[slot];
        tgt[3*idx] = cl.x; tgt[3*idx+1] = cl.y; tgt[3*idx+2] = cl.z;
        float tox = __fsub_rn(cl.x, gx), toy = __fsub_rn(cl.y, gy), toz = __fsub_rn(cl.z, gz);
        float ssq = __fadd_rn(__fadd_rn(__fmul_rn(tox,tox), __fmul_rn(toy,toy)),
                              __fmul_rn(toz,toz));
        m = (ssq > 0.f) ? sqrtf(ssq) : 0.f;
      }
      mag[idx] = m;
      atomicAdd(&h[__float_as_uint(m) >> 21], 1);
    }
    __syncthreads();
  }
  for (int t = threadIdx.x; t < HB; t += 256) {
    int cv = h[t];
    if (cv != 0) atomicAdd(&ghist[t], cv);
  }
}

// ---------------- K7b: find coarse bins of r0, r1 from the single global hist ----
__global__ void __launch_bounds__(1024) k_redsel(const int* __restrict__ ghist,
                                                 Scalars* sc, int r0, int r1) {
  __shared__ int ws[16];
  __shared__ int sBinA, sRA, sBinB, sRB;
  int t = threadIdx.x;
  int2 v = ((const int2*)ghist)[t];
  int s0 = v.x, s1 = v.y;
  int tot;
  int incl = block_scan_i(s0 + s1, ws, &tot);
  int b1 = incl - s1, b0 = b1 - s0;
  if (r0 >= b0 && r0 < b0 + s0) { sBinA = 2*t;   sRA = r0 - b0; }
  if (r0 >= b1 && r0 < b1 + s1) { sBinA = 2*t+1; sRA = r0 - b1; }
  if (r1 >= b0 && r1 < b0 + s0) { sBinB = 2*t;   sRB = r1 - b0; }
  if (r1 >= b1 && r1 < b1 + s1) { sBinB = 2*t+1; sRB = r1 - b1; }
  __syncthreads();
  if (t == 0) { sc->binA = sBinA; sc->rA = sRA; sc->binB = sBinB; sc->rB = sRB; }
}

// ---------------- K7c: gather candidate bit-patterns for the two coarse bins -----
__global__ void k_gather(const float* __restrict__ mag, const Scalars* sc,
                         unsigned* bufA, unsigned* bufB, int* cntAB, int n) {
  int i = blockIdx.x * blockDim.x + threadIdx.x;
  int lane = threadIdx.x & 63;
  unsigned bits = 0;
  bool inA = false, inB = false;
  if (i < n) {
    bits = __float_as_uint(mag[i]);
    unsigned c = bits >> 21;
    inA = (c == (unsigned)sc->binA);
    inB = (c == (unsigned)sc->binB);
  }
  {
    unsigned long long mb = __ballot(inA);
    int mc = __popcll(mb);
    int base = 0;
    if (lane == 0 && mc > 0) base = atomicAdd(&cntAB[0], mc);
    base = __shfl(base, 0, 64);
    if (inA) bufA[base + __popcll(mb & ((1ULL << lane) - 1ULL))] = bits;
  }
  {
    unsigned long long mb = __ballot(inB);
    int mc = __popcll(mb);
    int base = 0;
    if (lane == 0 && mc > 0) base = atomicAdd(&cntAB[1], mc);
    base = __shfl(base, 0, 64);
    if (inB) bufB[base + __popcll(mb & ((1ULL << lane) - 1ULL))] = bits;
  }
}

// ---------------- K7d helper: exact rank select within a coarse bin --------------
__device__ unsigned select_in_bin(const unsigned* __restrict__ buf, int cnt,
                                  int coarse, int rank, int* h, int* ws) {
  __shared__ int sSub, sSubR, sLow;
  for (int t = threadIdx.x; t < HB; t += 1024) h[t] = 0;
  __syncthreads();
  for (int t = threadIdx.x; t < cnt; t += 1024)
    atomicAdd(&h[(buf[t] >> 10) & 0x7FF], 1);
  __syncthreads();
  int t = threadIdx.x;
  int s0 = h[2*t], s1 = h[2*t+1];
  int tot;
  int incl = block_scan_i(s0 + s1, ws, &tot);
  int b1 = incl - s1, b0 = b1 - s0;
  if (rank >= b0 && rank < b0 + s0) { sSub = 2*t;   sSubR = rank - b0; }
  if (rank >= b1 && rank < b1 + s1) { sSub = 2*t+1; sSubR = rank - b1; }
  __syncthreads();
  int subv = sSub, subr = sSubR;
  h[t] = 0;
  __syncthreads();
  for (int q = threadIdx.x; q < cnt; q += 1024) {
    unsigned v = buf[q];
    if ((int)((v >> 10) & 0x7FF) == subv) atomicAdd(&h[v & 0x3FF], 1);
  }
  __syncthreads();
  int c = h[t];
  int tot2;
  int incl2 = block_scan_i(c, ws, &tot2);
  int lb = incl2 - c;
  if (subr >= lb && subr < lb + c) sLow = t;
  __syncthreads();
  return ((unsigned)coarse << 21) | ((unsigned)subv << 10) | (unsigned)sLow;
}

// ---------------- K7d: exact order statistics + lerp (numpy branch) --------------
__global__ void __launch_bounds__(1024) k_sel(const unsigned* __restrict__ bufA,
                                              const unsigned* __restrict__ bufB,
                                              const int* __restrict__ cntAB,
                                              Scalars* sc, double tfrac) {
  __shared__ int h[HB];
  __shared__ int ws[16];
  unsigned va = select_in_bin(bufA, cntAB[0], sc->binA, sc->rA, h, ws);
  __syncthreads();
  unsigned vb = select_in_bin(bufB, cntAB[1], sc->binB, sc->rB, h, ws);
  if (threadIdx.x == 0) {
    double a = (double)__uint_as_float(va);
    double b = (double)__uint_as_float(vb);
    double th = (tfrac >= 0.5) ? (b - (b - a) * (1.0 - tfrac)) : (a + (b - a) * tfrac);
    sc->thresh = (float)th;
  }
}

// ---------------- K8: masked huber + cosine reductions ---------------------------
__global__ void k_loss(const float* __restrict__ pred, const float* __restrict__ grid,
                       const float* __restrict__ tgt, const float* __restrict__ mag,
                       Scalars* sc, int n) {
  __shared__ double shH[256];
  __shared__ double shC[256];
  __shared__ int shN[256];
  __shared__ int shM[256];
  int tid = threadIdx.x;
  int i = blockIdx.x * blockDim.x + tid;
  double hub = 0.0, cs = 0.0;
  int c1 = 0, cmd = 0;
  if (i < n) {
    float th = sc->thresh;
    float m = mag[i];
    if (m <= th) {
      c1 = 1;
      float tox = __fsub_rn(tgt[3*i],   grid[3*i]);
      float toy = __fsub_rn(tgt[3*i+1], grid[3*i+1]);
      float toz = __fsub_rn(tgt[3*i+2], grid[3*i+2]);
      float px = pred[3*i], py = pred[3*i+1], pz = pred[3*i+2];
      float d0 = __fsub_rn(px, tox), d1 = __fsub_rn(py, toy), d2 = __fsub_rn(pz, toz);
      float a0 = fabsf(d0), a1 = fabsf(d1), a2 = fabsf(d2);
      float h0 = (a0 < 1.f) ? __fmul_rn(__fmul_rn(0.5f, d0), d0) : __fsub_rn(a0, 0.5f);
      float h1 = (a1 < 1.f) ? __fmul_rn(__fmul_rn(0.5f, d1), d1) : __fsub_rn(a1, 0.5f);
      float h2 = (a2 < 1.f) ? __fmul_rn(__fmul_rn(0.5f, d2), d2) : __fsub_rn(a2, 0.5f);
      hub = (double)h0 + (double)h1 + (double)h2;
      if (m > 0.f) {
        cmd = 1;
        float ps = __fadd_rn(__fadd_rn(__fmul_rn(px,px), __fmul_rn(py,py)), __fmul_rn(pz,pz));
        float pn = (ps > 0.f) ? sqrtf(ps) : 0.f;
        float dotp = __fadd_rn(__fadd_rn(__fmul_rn(px,tox), __fmul_rn(py,toy)),
                               __fmul_rn(pz,toz));
        float den = fmaxf(__fmul_rn(pn, m), 1e-4f);
        cs = (double)__fdiv_rn(dotp, den);
      }
    }
  }
  shH[tid] = hub; shC[tid] = cs; shN[tid] = c1; shM[tid] = cmd;
  __syncthreads();
  for (int off = 128; off > 0; off >>= 1) {
    if (tid < off) {
      shH[tid] += shH[tid+off];
      shC[tid] += shC[tid+off];
      shN[tid] += shN[tid+off];
      shM[tid] += shM[tid+off];
    }
    __syncthreads();
  }
  if (tid == 0) {
    atomicAdd(&sc->hub, shH[0]);
    atomicAdd(&sc->cosSum, shC[0]);
    atomicAdd(&sc->n1, shN[0]);
    atomicAdd(&sc->nmd, shM[0]);
  }
}

// ---------------- K9: finalize ---------------------------------------------------
__global__ void k_final(const Scalars* sc, float* out) {
  double n1 = (double)sc->n1;
  double l1 = (sc->n1 > 0) ? (sc->hub / fmax(n1 * 3.0, 1.0)) : 0.0;
  double nmd = (double)sc->nmd;
  double ld = (sc->nmd > 0) ? (1.0 - sc->cosSum / fmax(nmd, 1.0)) : 0.0;
  out[0] = (float)l1;
  out[1] = (float)ld;
}

extern "C" void kernel_launch(void* const* d_in, const int* in_sizes, int n_in,
                              void* d_out, int out_size, void* d_ws, size_t ws_size,
                              hipStream_t stream) {
  const float* pred  = (const float*)d_in[0];
  const float* grid  = (const float*)d_in[1];
  const int*   label = (const int*)d_in[2];
  const int*   batch = (const int*)d_in[3];
  int n = in_sizes[2];
  int mstride = n / 4;

  char* p = (char*)d_ws;
  auto take = [&](size_t bytes) -> char* {
    char* r = p;
    p += (bytes + 255) & ~(size_t)255;
    return r;
  };
  // ---- zero-init region (one hipMemsetAsync covers all of it) ----
  char* zbase = p;
  int*    cnt      = (int*)   take((size_t)SLOTS*4);
  float*  sx       = (float*) take((size_t)SLOTS*4);
  float*  sy       = (float*) take((size_t)SLOTS*4);
  float*  sz       = (float*) take((size_t)SLOTS*4);
  int*    lmask    = (int*)   take((size_t)SLOTS*4);
  int*    codeCnt  = (int*)   take(NCODE*4);
  int*    missCnt  = (int*)   take(NCODE*4);
  int*    blCnt    = (int*)   take(16*4);
  float*  blSum    = (float*) take(48*4);
  int*    cntAB    = (int*)   take(2*4);
  int*    ghist    = (int*)   take((size_t)HB*4);
  Scalars* sc      = (Scalars*)take(sizeof(Scalars));
  size_t zbytes = (size_t)(p - zbase);
  // ---- uninitialized buffers ----
  float4* ctr      = (float4*)take((size_t)SLOTS*16);
  float4* pC       = (float4*)take((size_t)NCODE*CSTRIDE*16);
  int*    pSlot    = (int*)   take((size_t)NCODE*CSTRIDE*4);
  unsigned* bufA   = (unsigned*)take((size_t)n*4);
  unsigned* bufB   = (unsigned*)take((size_t)n*4);
  float*  tgt      = (float*) take((size_t)n*3*4);
  float*  mag      = (float*) take((size_t)n*4);
  int*    missPart = (int*)   take((size_t)NCODE*mstride*4);

  int nb = (n + 255) / 256;

  hipMemsetAsync(zbase, 0, zbytes, stream);
  k_scatter<<<nb, 256, 0, stream>>>(grid, label, batch, cnt, sx, sy, sz, lmask,
                                    blCnt, blSum, n);
  k_prep<<<NBLK, 256, 0, stream>>>(cnt, sx, sy, sz, lmask, ctr, pC, pSlot, codeCnt);
  k_targets<<<nb, 256, 0, stream>>>(grid, label, batch, ctr, blCnt, blSum,
                                    tgt, mag, ghist, missPart, missCnt, mstride, n);
  k_fallback<<<NCODE * FBK, 256, 0, stream>>>(grid, pC, pSlot, ctr, codeCnt,
                                              missPart, missCnt, tgt, mag, ghist,
                                              mstride);

  double vi = 0.99 * (double)(n - 1);
  int r0 = (int)vi;
  int r1 = r0 + 1; if (r1 > n - 1) r1 = n - 1;
  double tfrac = vi - (double)r0;

  k_redsel<<<1, 1024, 0, stream>>>(ghist, sc, r0, r1);
  k_gather<<<nb, 256, 0, stream>>>(mag, sc, bufA, bufB, cntAB, n);
  k_sel<<<1, 1024, 0, stream>>>(bufA, bufB, cntAB, sc, tfrac);
  k_loss<<<nb, 256, 0, stream>>>(pred, grid, tgt, mag, sc, n);
  k_final<<<1, 1, 0, stream>>>(sc, (float*)d_out);
}